// Round 6
// baseline (108.170 us; speedup 1.0000x reference)
//
#include <hip/hip_runtime.h>
#include <math.h>

// Problem constants (B=1)
#define S 2048
#define DM 512
#define WIN 64
#define NX (S * DM)                        // 1,048,576
#define ATTN_SCALE 0.17677669529663687f    // 1/sqrt(32)
#define QSCALE 0.25500526964836844f        // ATTN_SCALE * log2(e)

typedef __attribute__((ext_vector_type(8))) short short8;   // 8 x bf16 (4 VGPR)
typedef __attribute__((ext_vector_type(4))) float floatx4;  // MFMA acc

__device__ __forceinline__ unsigned short f2bf(float f) {
  unsigned int u = __float_as_uint(f);
  unsigned int r = (u + 0x7FFFu + ((u >> 16) & 1u)) >> 16;   // RNE
  return (unsigned short)r;
}

// Raw v_exp_f32 (2^x). gfx9-lineage VALU is interlocked; single VOP1.
__device__ __forceinline__ float fast_exp2(float x) {
  float r;
  asm("v_exp_f32 %0, %1" : "=v"(r) : "v"(x));
  return r;
}

// ---------------------------------------------------------------------------
// Convert x (S*DM floats) and Wq|Wk|Wv|Wo (4 * DM*DM) to bf16.
// ---------------------------------------------------------------------------
__global__ __launch_bounds__(256) void convert_bf16(
    const float* __restrict__ x, const float* __restrict__ Wq,
    const float* __restrict__ Wk, const float* __restrict__ Wv,
    const float* __restrict__ Wo,
    unsigned short* __restrict__ xbf, unsigned short* __restrict__ wbf) {
  size_t i4 = ((size_t)blockIdx.x * 256 + threadIdx.x) * 4;
  const float* src; unsigned short* dst; size_t off;
  if (i4 < (size_t)NX) {
    src = x; dst = xbf; off = i4;
  } else {
    size_t r = i4 - (size_t)NX;
    int wsel = (int)(r >> 18);                // / (512*512)
    src = wsel == 0 ? Wq : wsel == 1 ? Wk : wsel == 2 ? Wv : Wo;
    dst = wbf + ((size_t)wsel << 18);
    off = r & 262143;
  }
  float4 f = *(const float4*)(src + off);
  ushort4 o;
  o.x = f2bf(f.x); o.y = f2bf(f.y); o.z = f2bf(f.z); o.w = f2bf(f.w);
  *(ushort4*)(dst + off) = o;
}

// ---------------------------------------------------------------------------
// 128x128 bf16 MFMA GEMM (QKV): C[M,N] = A[M,K] * B[N,K]^T, fp32 out.
// 4 waves in 2x2, each wave owns 64x64 = 4x4 of mfma_f32_16x16x32_bf16.
// LDS bytes per MFMA halves vs the 64^2 tile (fragment reuse 4x vs 2x):
// per K-tile: 32 KB staged + 64 KB frag reads for 128 MFMA-instr
// (0.75 KB/MFMA vs 1.5) -- the 64^2 loop is LDS-pipe-bound ~3.5:1.
// Same granule XOR-swizzle and T14 stage-split pipeline as the 64^2 kernel.
// ---------------------------------------------------------------------------
__global__ __launch_bounds__(256) void gemm_bf16_128(
    const unsigned short* __restrict__ Abf,
    const unsigned short* __restrict__ Bbase, int bstride,
    float* __restrict__ Cbase, int cstride, int N, int K) {
  __shared__ unsigned short As[128 * 64];
  __shared__ unsigned short Bs[128 * 64];

  const unsigned short* B = Bbase + (size_t)blockIdx.z * bstride;
  float* C = Cbase + (size_t)blockIdx.z * cstride;

  const int row0 = blockIdx.y * 128;
  const int col0 = blockIdx.x * 128;
  const int tid  = threadIdx.x;
  const int lane = tid & 63;
  const int w    = tid >> 6;       // wave id 0..3
  const int wr   = w >> 1;         // wave row 0..1
  const int wc   = w & 1;          // wave col 0..1
  const int quad = lane >> 4;      // 0..3
  const int lc   = lane & 15;

  // staging map: thread -> (row srow+32c, granule tid&7), 4 chunks of 32 rows
  const int srow = tid >> 3;                   // 0..31
  const int sg   = tid & 7;
  const int scol = sg * 8;
  const int sw0  = (sg ^ (srow & 7)) * 8;      // (srow+32c)&7 == srow&7

  const unsigned short* pa[4];
  const unsigned short* pb[4];
#pragma unroll
  for (int cth = 0; cth < 4; ++cth) {
    pa[cth] = &Abf[(size_t)(row0 + srow + 32 * cth) * K + scol];
    pb[cth] = &B[(size_t)(col0 + srow + 32 * cth) * K + scol];
  }

  floatx4 acc[4][4] = {};

  // prologue: K-tile 0 into registers
  short8 ar[4], br[4];
#pragma unroll
  for (int cth = 0; cth < 4; ++cth) {
    ar[cth] = *(const short8*)pa[cth];
    br[cth] = *(const short8*)pb[cth];
  }

  for (int k0 = 0; k0 < K; k0 += 64) {
    __syncthreads();   // previous iteration's LDS reads complete
#pragma unroll
    for (int cth = 0; cth < 4; ++cth) {
      *(short8*)&As[(srow + 32 * cth) * 64 + sw0] = ar[cth];
      *(short8*)&Bs[(srow + 32 * cth) * 64 + sw0] = br[cth];
    }
    __syncthreads();

    if (k0 + 64 < K) {   // issue next K-tile loads; latency hides under MFMA
#pragma unroll
      for (int cth = 0; cth < 4; ++cth) {
        ar[cth] = *(const short8*)(pa[cth] + k0 + 64);
        br[cth] = *(const short8*)(pb[cth] + k0 + 64);
      }
    }

#pragma unroll
    for (int s = 0; s < 2; ++s) {
      const int gk = s * 4 + quad;            // k-granule 0..7
      short8 aF[4], bF[4];
#pragma unroll
      for (int i = 0; i < 4; ++i) {
        int m = wr * 64 + i * 16 + lc;
        aF[i] = *(const short8*)&As[m * 64 + (gk ^ (m & 7)) * 8];
      }
#pragma unroll
      for (int j = 0; j < 4; ++j) {
        int n = wc * 64 + j * 16 + lc;
        bF[j] = *(const short8*)&Bs[n * 64 + (gk ^ (n & 7)) * 8];
      }
#pragma unroll
      for (int i = 0; i < 4; ++i)
#pragma unroll
        for (int j = 0; j < 4; ++j)
          acc[i][j] = __builtin_amdgcn_mfma_f32_16x16x32_bf16(
              aF[i], bF[j], acc[i][j], 0, 0, 0);
    }
  }

  // C/D layout: col = lane&15, row = quad*4 + reg  [verified m89/m91]
#pragma unroll
  for (int i = 0; i < 4; ++i)
#pragma unroll
    for (int j = 0; j < 4; ++j) {
      int col = col0 + wc * 64 + j * 16 + lc;
#pragma unroll
      for (int r = 0; r < 4; ++r) {
        int row = row0 + wr * 64 + i * 16 + quad * 4 + r;
        C[(size_t)row * N + col] = acc[i][j][r];
      }
    }
}

// ---------------------------------------------------------------------------
// 64x64 bf16 MFMA GEMM (proj: grid would be only 64 blocks at 128^2 --
// fewer active CUs with double per-block depth loses; keep 256 blocks).
// T14 stage-split pipeline, granule XOR-swizzle (verified R4 body).
// ---------------------------------------------------------------------------
__global__ __launch_bounds__(256) void gemm_bf16(
    const unsigned short* __restrict__ Abf,
    const unsigned short* __restrict__ Bbase, int bstride,
    float* __restrict__ Cbase, int cstride, int N, int K) {
  __shared__ unsigned short As[64 * 64];
  __shared__ unsigned short Bs[64 * 64];

  const unsigned short* B = Bbase + (size_t)blockIdx.z * bstride;
  float* C = Cbase + (size_t)blockIdx.z * cstride;

  const int row0 = blockIdx.y * 64;
  const int col0 = blockIdx.x * 64;
  const int tid  = threadIdx.x;
  const int lane = tid & 63;
  const int w    = tid >> 6;       // wave id 0..3
  const int wr   = w >> 1;         // wave row 0..1
  const int wc   = w & 1;          // wave col 0..1
  const int quad = lane >> 4;      // 0..3
  const int lc   = lane & 15;

  const int srow = tid >> 3;
  const int sg   = tid & 7;
  const int scol = sg * 8;
  const int sw0  = (sg ^ (srow & 7)) * 8;

  const unsigned short* pa0 = &Abf[(size_t)(row0 + srow) * K + scol];
  const unsigned short* pa1 = &Abf[(size_t)(row0 + srow + 32) * K + scol];
  const unsigned short* pb0 = &B[(size_t)(col0 + srow) * K + scol];
  const unsigned short* pb1 = &B[(size_t)(col0 + srow + 32) * K + scol];

  floatx4 acc[2][2] = {};

  short8 a0 = *(const short8*)pa0;
  short8 a1 = *(const short8*)pa1;
  short8 b0 = *(const short8*)pb0;
  short8 b1 = *(const short8*)pb1;

  for (int k0 = 0; k0 < K; k0 += 64) {
    __syncthreads();
    *(short8*)&As[srow * 64 + sw0] = a0;
    *(short8*)&As[(srow + 32) * 64 + sw0] = a1;
    *(short8*)&Bs[srow * 64 + sw0] = b0;
    *(short8*)&Bs[(srow + 32) * 64 + sw0] = b1;
    __syncthreads();

    if (k0 + 64 < K) {
      a0 = *(const short8*)(pa0 + k0 + 64);
      a1 = *(const short8*)(pa1 + k0 + 64);
      b0 = *(const short8*)(pb0 + k0 + 64);
      b1 = *(const short8*)(pb1 + k0 + 64);
    }

#pragma unroll
    for (int s = 0; s < 2; ++s) {
      const int gk = s * 4 + quad;
      short8 aF[2], bF[2];
#pragma unroll
      for (int i = 0; i < 2; ++i) {
        int m = wr * 32 + i * 16 + lc;
        aF[i] = *(const short8*)&As[m * 64 + (gk ^ (m & 7)) * 8];
      }
#pragma unroll
      for (int j = 0; j < 2; ++j) {
        int n = wc * 32 + j * 16 + lc;
        bF[j] = *(const short8*)&Bs[n * 64 + (gk ^ (n & 7)) * 8];
      }
#pragma unroll
      for (int i = 0; i < 2; ++i)
#pragma unroll
        for (int j = 0; j < 2; ++j)
          acc[i][j] = __builtin_amdgcn_mfma_f32_16x16x32_bf16(
              aF[i], bF[j], acc[i][j], 0, 0, 0);
    }
  }

#pragma unroll
  for (int i = 0; i < 2; ++i)
#pragma unroll
    for (int j = 0; j < 2; ++j) {
      int col = col0 + wc * 32 + j * 16 + lc;
#pragma unroll
      for (int r = 0; r < 4; ++r) {
        int row = row0 + wr * 32 + i * 16 + quad * 4 + r;
        C[(size_t)row * N + col] = acc[i][j][r];
      }
    }
}

// ---------------------------------------------------------------------------
// Sliding-window per-channel softmax, LDS-tiled, issue-slimmed (R4 body).
// ---------------------------------------------------------------------------
#define SWIN_ITEM(EDGE)                                                       \
  {                                                                           \
    float l0 = 0.f, l1 = 0.f, l2 = 0.f, l3 = 0.f;                             \
    float a0 = 0.f, a1 = 0.f, a2 = 0.f, a3 = 0.f;                             \
    _Pragma("unroll 4")                                                       \
    for (int jj = 0; jj < WIN; jj += 4) {                                     \
      _Pragma("unroll")                                                       \
      for (int u = 0; u < 4; ++u) {                                           \
        const float2 kv2 = kvs[base + (jj + u) * 33];                         \
        float p = fast_exp2(qvl * kv2.x);                                     \
        if (EDGE) p = (jj + u >= th) ? p : 0.f;                               \
        if (u == 0)      { l0 += p; a0 = fmaf(p, kv2.y, a0); }                \
        else if (u == 1) { l1 += p; a1 = fmaf(p, kv2.y, a1); }                \
        else if (u == 2) { l2 += p; a2 = fmaf(p, kv2.y, a2); }                \
        else             { l3 += p; a3 = fmaf(p, kv2.y, a3); }                \
      }                                                                       \
    }                                                                         \
    const float r = (a0 + a1 + a2 + a3) / (l0 + l1 + l2 + l3);                \
    o[(size_t)(i0 + ii) * DM + c] = f2bf(r);                                  \
  }

__global__ __launch_bounds__(256) void swin_attn_tiled(
    const float* __restrict__ q, const float* __restrict__ k,
    const float* __restrict__ v, unsigned short* __restrict__ o) {
  __shared__ float2 kvs[127 * 33];     // 33.5 KB, padded row stride

  const int i0 = blockIdx.y * 64;      // query-row tile
  const int c0 = blockIdx.x * 32;      // channel tile
  const int t  = threadIdx.x;

  for (int vi = t; vi < 127 * 8; vi += 256) {
    const int r = vi >> 3;                       // panel row 0..126
    const int g = vi & 7;                        // float4 within row
    int gr = i0 - 63 + r;
    gr = gr < 0 ? 0 : gr;                        // clamp (masked in compute)
    const float4 kf = *(const float4*)(k + (size_t)gr * DM + c0 + g * 4);
    const float4 vf = *(const float4*)(v + (size_t)gr * DM + c0 + g * 4);
    float2* dst = &kvs[r * 33 + g * 4];
    dst[0] = make_float2(kf.x, vf.x);
    dst[1] = make_float2(kf.y, vf.y);
    dst[2] = make_float2(kf.z, vf.z);
    dst[3] = make_float2(kf.w, vf.w);
  }
  __syncthreads();

  const int cl = t & 31;
  const int c  = c0 + cl;

  if (blockIdx.y == 0) {
#pragma unroll
    for (int item = 0; item < 8; ++item) {
      const int ii = (t >> 5) + item * 8;                 // 0..63
      const float qvl = q[(size_t)(i0 + ii) * DM + c] * QSCALE;
      const int base = ii * 33 + cl;
      const int th = 63 - ii;                             // jj >= th is valid
      SWIN_ITEM(true)
    }
  } else {
#pragma unroll
    for (int item = 0; item < 8; ++item) {
      const int ii = (t >> 5) + item * 8;
      const float qvl = q[(size_t)(i0 + ii) * DM + c] * QSCALE;
      const int base = ii * 33 + cl;
      const int th = 0;                                   // unused
      SWIN_ITEM(false)
    }
  }
}

// ---------------------------------------------------------------------------
// Launch — proven 4-dispatch structure.
// ---------------------------------------------------------------------------
extern "C" void kernel_launch(void* const* d_in, const int* in_sizes, int n_in,
                              void* d_out, int out_size, void* d_ws, size_t ws_size,
                              hipStream_t stream) {
  const float* x  = (const float*)d_in[0];
  const float* Wq = (const float*)d_in[1];
  const float* Wk = (const float*)d_in[2];
  const float* Wv = (const float*)d_in[3];
  const float* Wo = (const float*)d_in[4];
  float* out = (float*)d_out;

  // ws layout (16 MB):
  //   q, k, v : 3 x 1M fp32 (12 MB)
  //   xbf     : 1M bf16 (2 MB)  -- reused as attn_bf16 after QKV GEMM
  //   wbf     : 4 x 256K bf16 (2 MB)
  float* q = (float*)d_ws;
  float* kk = q + (size_t)NX;
  float* vv = kk + (size_t)NX;
  unsigned short* xbf = (unsigned short*)(vv + (size_t)NX);
  unsigned short* wbf = xbf + (size_t)NX;
  unsigned short* attnbf = xbf;   // reuse after x is consumed

  // 1) fp32 -> bf16 conversions (2M elements, 4/thread)
  convert_bf16<<<dim3(2048), dim3(256), 0, stream>>>(x, Wq, Wk, Wv, Wo, xbf, wbf);

  // 2) fused QKV: C_z = x * W_z^T, z = 0,1,2  (128^2 tiles, 192 blocks)
  gemm_bf16_128<<<dim3(DM / 128, S / 128, 3), dim3(256), 0, stream>>>(
      xbf, wbf, DM * DM, q, S * DM, DM, DM);

  // 3) sliding-window per-channel softmax (LDS-tiled) -> bf16
  swin_attn_tiled<<<dim3(DM / 32, S / 64), dim3(256), 0, stream>>>(
      q, kk, vv, attnbf);

  // 4) output projection: out = attn * Wo^T  (64^2 tiles, 256 blocks)
  gemm_bf16<<<dim3(DM / 64, S / 64, 1), dim3(256), 0, stream>>>(
      attnbf, wbf + 3 * (size_t)DM * DM, 0, out, 0, DM, DM);
}

// Round 7
// 107.573 us; speedup vs baseline: 1.0056x; 1.0056x over previous
//
#include <hip/hip_runtime.h>
#include <math.h>

// Problem constants (B=1)
#define S 2048
#define DM 512
#define WIN 64
#define NX (S * DM)                        // 1,048,576
#define ATTN_SCALE 0.17677669529663687f    // 1/sqrt(32)
#define QSCALE 0.25500526964836844f        // ATTN_SCALE * log2(e)

typedef __attribute__((ext_vector_type(8))) short short8;   // 8 x bf16 (4 VGPR)
typedef __attribute__((ext_vector_type(4))) float floatx4;  // MFMA acc

__device__ __forceinline__ unsigned short f2bf(float f) {
  unsigned int u = __float_as_uint(f);
  unsigned int r = (u + 0x7FFFu + ((u >> 16) & 1u)) >> 16;   // RNE
  return (unsigned short)r;
}

// Raw v_exp_f32 (2^x). gfx9-lineage VALU is interlocked; single VOP1.
__device__ __forceinline__ float fast_exp2(float x) {
  float r;
  asm("v_exp_f32 %0, %1" : "=v"(r) : "v"(x));
  return r;
}

// ---------------------------------------------------------------------------
// Convert x (S*DM floats) and Wq|Wk|Wv|Wo (4 * DM*DM) to bf16.
// ---------------------------------------------------------------------------
__global__ __launch_bounds__(256) void convert_bf16(
    const float* __restrict__ x, const float* __restrict__ Wq,
    const float* __restrict__ Wk, const float* __restrict__ Wv,
    const float* __restrict__ Wo,
    unsigned short* __restrict__ xbf, unsigned short* __restrict__ wbf) {
  size_t i4 = ((size_t)blockIdx.x * 256 + threadIdx.x) * 4;
  const float* src; unsigned short* dst; size_t off;
  if (i4 < (size_t)NX) {
    src = x; dst = xbf; off = i4;
  } else {
    size_t r = i4 - (size_t)NX;
    int wsel = (int)(r >> 18);                // / (512*512)
    src = wsel == 0 ? Wq : wsel == 1 ? Wk : wsel == 2 ? Wv : Wo;
    dst = wbf + ((size_t)wsel << 18);
    off = r & 262143;
  }
  float4 f = *(const float4*)(src + off);
  ushort4 o;
  o.x = f2bf(f.x); o.y = f2bf(f.y); o.z = f2bf(f.z); o.w = f2bf(f.w);
  *(ushort4*)(dst + off) = o;
}

// ---------------------------------------------------------------------------
// bf16 MFMA GEMM: C[M,N] = A[M,K] * B[N,K]^T  (fp32 accumulate/output).
// 64x64 tile, BK=64, 4 waves in 2x2, each wave 32x32 via 2x2 of
// mfma_f32_16x16x32_bf16.  LDS granule XOR-swizzle: row r, granule g at
// g ^ (r & 7).
//
// T14 stage-split pipeline: registers hold K-tile t while LDS holds t-1.
//   barrier -> ds_write regs(t) -> barrier -> ISSUE loads(t+1) -> compute(t)
// (R6 showed the 128^2 tile loses here: 192 blocks < 256 CUs -- CU-coverage
//  loss cancels the per-MFMA LDS-traffic win at this problem shape.)
// ---------------------------------------------------------------------------
__global__ __launch_bounds__(256) void gemm_bf16(
    const unsigned short* __restrict__ Abf,
    const unsigned short* __restrict__ Bbase, int bstride,
    float* __restrict__ Cbase, int cstride, int N, int K) {
  __shared__ unsigned short As[64 * 64];
  __shared__ unsigned short Bs[64 * 64];

  const unsigned short* B = Bbase + (size_t)blockIdx.z * bstride;
  float* C = Cbase + (size_t)blockIdx.z * cstride;

  const int row0 = blockIdx.y * 64;
  const int col0 = blockIdx.x * 64;
  const int tid  = threadIdx.x;
  const int lane = tid & 63;
  const int w    = tid >> 6;       // wave id 0..3
  const int wr   = w >> 1;         // wave row 0..1
  const int wc   = w & 1;          // wave col 0..1
  const int quad = lane >> 4;      // 0..3
  const int lc   = lane & 15;

  // staging map: thread -> (row srow, 16B granule tid&7), covers 32 rows/pass
  const int srow = tid >> 3;
  const int sg   = tid & 7;                    // granule within row
  const int scol = sg * 8;                     // element col in global tile
  const int sw0  = (sg ^ (srow & 7)) * 8;      // swizzled LDS elem col

  const unsigned short* pa0 = &Abf[(size_t)(row0 + srow) * K + scol];
  const unsigned short* pa1 = &Abf[(size_t)(row0 + srow + 32) * K + scol];
  const unsigned short* pb0 = &B[(size_t)(col0 + srow) * K + scol];
  const unsigned short* pb1 = &B[(size_t)(col0 + srow + 32) * K + scol];

  floatx4 acc[2][2] = {};

  // prologue: K-tile 0 into registers
  short8 a0 = *(const short8*)pa0;
  short8 a1 = *(const short8*)pa1;
  short8 b0 = *(const short8*)pb0;
  short8 b1 = *(const short8*)pb1;

  for (int k0 = 0; k0 < K; k0 += 64) {
    __syncthreads();   // previous iteration's LDS reads complete
    *(short8*)&As[srow * 64 + sw0] = a0;
    *(short8*)&As[(srow + 32) * 64 + sw0] = a1;   // (srow+32)&7 == srow&7
    *(short8*)&Bs[srow * 64 + sw0] = b0;
    *(short8*)&Bs[(srow + 32) * 64 + sw0] = b1;
    __syncthreads();

    if (k0 + 64 < K) {   // issue next K-tile loads; latency hides under MFMA
      a0 = *(const short8*)(pa0 + k0 + 64);
      a1 = *(const short8*)(pa1 + k0 + 64);
      b0 = *(const short8*)(pb0 + k0 + 64);
      b1 = *(const short8*)(pb1 + k0 + 64);
    }

#pragma unroll
    for (int s = 0; s < 2; ++s) {
      const int gk = s * 4 + quad;            // k-granule 0..7
      short8 aF[2], bF[2];
#pragma unroll
      for (int i = 0; i < 2; ++i) {
        int m = wr * 32 + i * 16 + lc;
        aF[i] = *(const short8*)&As[m * 64 + (gk ^ (m & 7)) * 8];
      }
#pragma unroll
      for (int j = 0; j < 2; ++j) {
        int n = wc * 32 + j * 16 + lc;
        bF[j] = *(const short8*)&Bs[n * 64 + (gk ^ (n & 7)) * 8];
      }
#pragma unroll
      for (int i = 0; i < 2; ++i)
#pragma unroll
        for (int j = 0; j < 2; ++j)
          acc[i][j] = __builtin_amdgcn_mfma_f32_16x16x32_bf16(
              aF[i], bF[j], acc[i][j], 0, 0, 0);
    }
  }

  // C/D layout: col = lane&15, row = quad*4 + reg  [verified m89/m91]
#pragma unroll
  for (int i = 0; i < 2; ++i)
#pragma unroll
    for (int j = 0; j < 2; ++j) {
      int col = col0 + wc * 32 + j * 16 + lc;
#pragma unroll
      for (int r = 0; r < 4; ++r) {
        int row = row0 + wr * 32 + i * 16 + quad * 4 + r;
        C[(size_t)row * N + col] = acc[i][j][r];
      }
    }
}

// ---------------------------------------------------------------------------
// Sliding-window per-channel softmax, LDS-tiled, issue-slimmed.
// Block = 64 query rows x 32 channels; stages k/v rows [i0-63, i0+63].
// k,v interleaved as float2 rows padded to 33 (row stride 264 B): both the
// b64 writes and the b64 reads land <=2 lanes/bank (free aliasing, m136).
// Per window item: 1 ds_read_b64 + mul + v_exp_f32 + fma + add
// (exp folded to exp2 with log2e pre-multiplied into the q scalar).
// ---------------------------------------------------------------------------
#define SWIN_ITEM(EDGE)                                                       \
  {                                                                           \
    float l0 = 0.f, l1 = 0.f, l2 = 0.f, l3 = 0.f;                             \
    float a0 = 0.f, a1 = 0.f, a2 = 0.f, a3 = 0.f;                             \
    _Pragma("unroll 4")                                                       \
    for (int jj = 0; jj < WIN; jj += 4) {                                     \
      _Pragma("unroll")                                                       \
      for (int u = 0; u < 4; ++u) {                                           \
        const float2 kv2 = kvs[base + (jj + u) * 33];                         \
        float p = fast_exp2(qvl * kv2.x);                                     \
        if (EDGE) p = (jj + u >= th) ? p : 0.f;                               \
        if (u == 0)      { l0 += p; a0 = fmaf(p, kv2.y, a0); }                \
        else if (u == 1) { l1 += p; a1 = fmaf(p, kv2.y, a1); }                \
        else if (u == 2) { l2 += p; a2 = fmaf(p, kv2.y, a2); }                \
        else             { l3 += p; a3 = fmaf(p, kv2.y, a3); }                \
      }                                                                       \
    }                                                                         \
    const float r = (a0 + a1 + a2 + a3) / (l0 + l1 + l2 + l3);                \
    o[(size_t)(i0 + ii) * DM + c] = f2bf(r);                                  \
  }

__global__ __launch_bounds__(256) void swin_attn_tiled(
    const float* __restrict__ q, const float* __restrict__ k,
    const float* __restrict__ v, unsigned short* __restrict__ o) {
  __shared__ float2 kvs[127 * 33];     // 33.5 KB, padded row stride

  const int i0 = blockIdx.y * 64;      // query-row tile
  const int c0 = blockIdx.x * 32;      // channel tile
  const int t  = threadIdx.x;

  for (int vi = t; vi < 127 * 8; vi += 256) {
    const int r = vi >> 3;                       // panel row 0..126
    const int g = vi & 7;                        // float4 within row
    int gr = i0 - 63 + r;
    gr = gr < 0 ? 0 : gr;                        // clamp (masked in compute)
    const float4 kf = *(const float4*)(k + (size_t)gr * DM + c0 + g * 4);
    const float4 vf = *(const float4*)(v + (size_t)gr * DM + c0 + g * 4);
    float2* dst = &kvs[r * 33 + g * 4];
    dst[0] = make_float2(kf.x, vf.x);
    dst[1] = make_float2(kf.y, vf.y);
    dst[2] = make_float2(kf.z, vf.z);
    dst[3] = make_float2(kf.w, vf.w);
  }
  __syncthreads();

  const int cl = t & 31;
  const int c  = c0 + cl;

  if (blockIdx.y == 0) {
#pragma unroll
    for (int item = 0; item < 8; ++item) {
      const int ii = (t >> 5) + item * 8;                 // 0..63
      const float qvl = q[(size_t)(i0 + ii) * DM + c] * QSCALE;
      const int base = ii * 33 + cl;
      const int th = 63 - ii;                             // jj >= th is valid
      SWIN_ITEM(true)
    }
  } else {
#pragma unroll
    for (int item = 0; item < 8; ++item) {
      const int ii = (t >> 5) + item * 8;
      const float qvl = q[(size_t)(i0 + ii) * DM + c] * QSCALE;
      const int base = ii * 33 + cl;
      const int th = 0;                                   // unused
      SWIN_ITEM(false)
    }
  }
}

// ---------------------------------------------------------------------------
// Launch — proven 4-dispatch structure (R2: overhead is fixed per-iteration,
// not per-dispatch; cooperative fusion regressed 2x).
// ---------------------------------------------------------------------------
extern "C" void kernel_launch(void* const* d_in, const int* in_sizes, int n_in,
                              void* d_out, int out_size, void* d_ws, size_t ws_size,
                              hipStream_t stream) {
  const float* x  = (const float*)d_in[0];
  const float* Wq = (const float*)d_in[1];
  const float* Wk = (const float*)d_in[2];
  const float* Wv = (const float*)d_in[3];
  const float* Wo = (const float*)d_in[4];
  float* out = (float*)d_out;

  // ws layout (16 MB):
  //   q, k, v : 3 x 1M fp32 (12 MB)
  //   xbf     : 1M bf16 (2 MB)  -- reused as attn_bf16 after QKV GEMM
  //   wbf     : 4 x 256K bf16 (2 MB)
  float* q = (float*)d_ws;
  float* kk = q + (size_t)NX;
  float* vv = kk + (size_t)NX;
  unsigned short* xbf = (unsigned short*)(vv + (size_t)NX);
  unsigned short* wbf = xbf + (size_t)NX;
  unsigned short* attnbf = xbf;   // reuse after x is consumed

  // 1) fp32 -> bf16 conversions (2M elements, 4/thread)
  convert_bf16<<<dim3(2048), dim3(256), 0, stream>>>(x, Wq, Wk, Wv, Wo, xbf, wbf);

  // 2) fused QKV: C_z = x * W_z^T, z = 0,1,2
  gemm_bf16<<<dim3(DM / 64, S / 64, 3), dim3(256), 0, stream>>>(
      xbf, wbf, DM * DM, q, S * DM, DM, DM);

  // 3) sliding-window per-channel softmax (LDS-tiled) -> bf16
  swin_attn_tiled<<<dim3(DM / 32, S / 64), dim3(256), 0, stream>>>(
      q, kk, vv, attnbf);

  // 4) output projection: out = attn * Wo^T
  gemm_bf16<<<dim3(DM / 64, S / 64, 1), dim3(256), 0, stream>>>(
      attnbf, wbf + 3 * (size_t)DM * DM, 0, out, 0, DM, DM);
}